// Round 2
// baseline (2030.088 us; speedup 1.0000x reference)
//
#include <hip/hip_runtime.h>

// ComplexNetAttention on gfx950.
// Pipeline: int8-fakequant -> fused complex QKV GEMM (fp16 MFMA, NT, K=4096)
//           -> RoPE (bf16 cos/sin to match ref) -> per-head scores GEMM (fp32)
//           -> causal softmax (P fp16 in-place) -> PV GEMM -> fakequant -> out GEMM.
// GEMM template: 128x128 tile, BK=32, 256 thr (4 waves, 2x2 of 64x64), 4x4
// MFMA 16x16x32_f16 per wave, global_load_lds width-16 staging, XOR-swizzled
// LDS chunk layout (kills the 8-way bank conflict of the 64B row stride).

typedef float v4f __attribute__((ext_vector_type(4)));
typedef _Float16 v8h __attribute__((ext_vector_type(8)));
typedef _Float16 v4h __attribute__((ext_vector_type(4)));

typedef const __attribute__((address_space(1))) void glob_void;
typedef __attribute__((address_space(3))) void lds_void;

__device__ __forceinline__ void gload16(const _Float16* gp, _Float16* lp) {
  __builtin_amdgcn_global_load_lds((glob_void*)gp, (lds_void*)lp, 16, 0, 0);
}

// bf16 round-trip (RNE) in fp32 — matches reference's bf16 cos/sin cache.
__device__ __forceinline__ float bf16_rt(float f) {
  union { float f; unsigned u; } a; a.f = f;
  unsigned r = (a.u + 0x7fffu + ((a.u >> 16) & 1u)) & 0xffff0000u;
  union { unsigned u; float f; } b; b.u = r;
  return b.f;
}

#define EPI_F16   0
#define EPI_SCORE 1
#define EPI_ATTN  2
#define EPI_OUT   3

// NT GEMM: C[M][N] = A[M][K] @ B[N][K]^T, fp16 in, fp32 acc.
// LDS layout: row r (32 halfs) split into 4 chunks of 8 halfs; chunk c stored
// at slot c ^ ((r>>1)&3). Quarter-wave fragment reads then hit each bank
// exactly 2x (free) instead of 8-way.
template<int EPI, bool SKIP_UPPER, bool CAUSAL_K>
__global__ __launch_bounds__(256) void gemm_nt(
    const _Float16* __restrict__ A, const _Float16* __restrict__ B,
    void* __restrict__ Cv, int M, int N, int K, int lda, int ldb, int ldc,
    long long aZ, long long bZ, long long cZ,
    float scale, float* __restrict__ attn, int h0)
{
  const int m0 = blockIdx.x * 128, n0 = blockIdx.y * 128;
  if (SKIP_UPPER && n0 >= m0 + 128) return;   // fully-masked causal block
  const int z = blockIdx.z;
  const _Float16* Ab = A + (long long)z * aZ;
  const _Float16* Bb = B + (long long)z * bZ;
  const int kend = CAUSAL_K ? ((m0 + 128 < K) ? (m0 + 128) : K) : K;

  __shared__ __align__(16) _Float16 As[128 * 32];
  __shared__ __align__(16) _Float16 Bs[128 * 32];

  const int tid = threadIdx.x, lane = tid & 63, wave = tid >> 6;
  // staging: tile 128 rows x 32 halfs = 8KB, 2 segs x 256 thr x 16B.
  // LDS dest is linear (wave-uniform + lane*16); the GLOBAL chunk fetched into
  // slot c' of row r is c' ^ ((r>>1)&3)  (XOR swizzle, involution).
  const int off0 = tid * 8, off1 = 2048 + tid * 8;
  const int r0 = off0 >> 5, r1 = off1 >> 5;
  const int c0 = ((((off0 >> 3) & 3) ^ ((r0 >> 1) & 3)) << 3);
  const int c1 = ((((off1 >> 3) & 3) ^ ((r1 >> 1) & 3)) << 3);
  const _Float16* ga0 = Ab + (long long)(m0 + r0) * lda + c0;
  const _Float16* ga1 = Ab + (long long)(m0 + r1) * lda + c1;
  const _Float16* gb0 = Bb + (long long)(n0 + r0) * ldb + c0;
  const _Float16* gb1 = Bb + (long long)(n0 + r1) * ldb + c1;

  const int mr = (wave >> 1) * 64 + (lane & 15);   // + i*16
  const int nr = (wave & 1) * 64 + (lane & 15);    // + j*16
  const int kq = lane >> 4;                        // logical chunk 0..3

  v4f acc[4][4] = {};

  for (int k0 = 0; k0 < kend; k0 += 32) {
    gload16(ga0 + k0, As + off0);
    gload16(ga1 + k0, As + off1);
    gload16(gb0 + k0, Bs + off0);
    gload16(gb1 + k0, Bs + off1);
    __syncthreads();   // compiler drains vmcnt before s_barrier
    v8h a[4], b[4];
#pragma unroll
    for (int i = 0; i < 4; ++i) {
      const int r = mr + i * 16;
      a[i] = *(const v8h*)&As[r * 32 + ((kq ^ ((r >> 1) & 3)) << 3)];
    }
#pragma unroll
    for (int j = 0; j < 4; ++j) {
      const int r = nr + j * 16;
      b[j] = *(const v8h*)&Bs[r * 32 + ((kq ^ ((r >> 1) & 3)) << 3)];
    }
#pragma unroll
    for (int i = 0; i < 4; ++i)
#pragma unroll
      for (int j = 0; j < 4; ++j)
        acc[i][j] = __builtin_amdgcn_mfma_f32_16x16x32_f16(a[i], b[j], acc[i][j], 0, 0, 0);
    __syncthreads();
  }

  // C/D layout (m89/m91-verified): col=lane&15, row=quad*4+reg
  const int cr = (wave >> 1) * 64 + (lane >> 4) * 4;
  const int cc = (wave & 1) * 64 + (lane & 15);
#pragma unroll
  for (int i = 0; i < 4; ++i)
#pragma unroll
    for (int j = 0; j < 4; ++j)
#pragma unroll
      for (int r = 0; r < 4; ++r) {
        const int row = m0 + cr + i * 16 + r;
        const int col = n0 + cc + j * 16;
        const float v = acc[i][j][r];
        if (EPI == EPI_F16) {
          ((_Float16*)Cv)[(long long)z * cZ + (long long)row * ldc + col] = (_Float16)v;
        } else if (EPI == EPI_SCORE) {
          ((float*)Cv)[(long long)z * cZ + (long long)row * ldc + col] = v * scale;
        } else if (EPI == EPI_ATTN) {
          const int half = col >> 7, d = col & 127;
          attn[(long long)half * M * 2048 + (long long)row * 2048 + (h0 + z) * 128 + d] = v;
        } else { // EPI_OUT: split columns [yr | yi] into concatenated outputs
          float* O = (float*)Cv;
          if (col < 2048) O[(long long)row * 2048 + col] = v;
          else O[(long long)M * 2048 + (long long)row * 2048 + (col - 2048)] = v;
        }
      }
}

// per-row int8 fake-quant of two [T][rowlen] fp32 sources -> fp16 [T][2*rowlen]
__global__ __launch_bounds__(256) void quant_rows(
    const float* __restrict__ s0, const float* __restrict__ s1,
    _Float16* __restrict__ dst, int rowlen, int dld)
{
  const int t = blockIdx.x, y = blockIdx.y;
  const float* src = (y ? s1 : s0) + (long long)t * rowlen;
  const int tid = threadIdx.x, lane = tid & 63, wave = tid >> 6;
  __shared__ float rbuf[4];
  float m = 0.f;
  for (int c = tid * 4; c < rowlen; c += 1024) {
    v4f v = *(const v4f*)(src + c);
    m = fmaxf(m, fmaxf(fmaxf(fabsf(v[0]), fabsf(v[1])), fmaxf(fabsf(v[2]), fabsf(v[3]))));
  }
  for (int o = 1; o < 64; o <<= 1) m = fmaxf(m, __shfl_xor(m, o, 64));
  if (lane == 0) rbuf[wave] = m;
  __syncthreads();
  m = fmaxf(fmaxf(rbuf[0], rbuf[1]), fmaxf(rbuf[2], rbuf[3]));
  const float scale = 127.f / fmaxf(m, 1e-5f);
  _Float16* d = dst + (long long)t * dld + (long long)y * rowlen;
  for (int c = tid * 4; c < rowlen; c += 1024) {
    v4f v = *(const v4f*)(src + c);
#pragma unroll
    for (int k = 0; k < 4; ++k) {
      float q = fminf(fmaxf(rintf(v[k] * scale), -128.f), 127.f);
      d[c + k] = (_Float16)(q / scale);
    }
  }
}

// Build concatenated complex weight matrices (fp16):
// Bqkv[12288][4096]: per source pair (Wr,Wi): rows [Wr|Wi] then [Wi|-Wr]
// Bo  [4096][4096] same from (Wo_r, Wo_i)
__global__ __launch_bounds__(256) void wprep(
    const float* __restrict__ Wq_r, const float* __restrict__ Wq_i,
    const float* __restrict__ Wk_r, const float* __restrict__ Wk_i,
    const float* __restrict__ Wv_r, const float* __restrict__ Wv_i,
    const float* __restrict__ Wo_r, const float* __restrict__ Wo_i,
    _Float16* __restrict__ Bqkv, _Float16* __restrict__ Bo)
{
  long long i4 = (long long)blockIdx.x * 256 + threadIdx.x;
  if (i4 >= 16384ll * 1024) return;
  int n = (int)(i4 >> 10);
  int c = ((int)i4 & 1023) * 4;
  const float *sA, *sB; float sg; _Float16* dst; int j;
  if (n < 12288) {
    int which = n >> 11; j = n & 2047;
    switch (which) {
      case 0: sA = Wq_r; sB = Wq_i; sg =  1.f; break;
      case 1: sA = Wq_i; sB = Wq_r; sg = -1.f; break;
      case 2: sA = Wk_r; sB = Wk_i; sg =  1.f; break;
      case 3: sA = Wk_i; sB = Wk_r; sg = -1.f; break;
      case 4: sA = Wv_r; sB = Wv_i; sg =  1.f; break;
      default: sA = Wv_i; sB = Wv_r; sg = -1.f; break;
    }
    dst = Bqkv + (long long)n * 4096;
  } else {
    int n2 = n - 12288; int which = n2 >> 11; j = n2 & 2047;
    if (which == 0) { sA = Wo_r; sB = Wo_i; sg = 1.f; }
    else            { sA = Wo_i; sB = Wo_r; sg = -1.f; }
    dst = Bo + (long long)n2 * 4096;
  }
  const float mult = (c < 2048) ? 1.f : sg;
  const float* src = (c < 2048) ? (sA + (long long)j * 2048 + c)
                                : (sB + (long long)j * 2048 + (c - 2048));
  v4f v = *(const v4f*)src;
  dst += c;
  dst[0] = (_Float16)(v[0] * mult); dst[1] = (_Float16)(v[1] * mult);
  dst[2] = (_Float16)(v[2] * mult); dst[3] = (_Float16)(v[3] * mult);
}

// RoPE on q,k (bf16-rounded cos/sin, matching ref) -> qc/kc [NH][T][256] fp16
__global__ __launch_bounds__(256) void rope_kernel(
    const _Float16* __restrict__ Y, const int* __restrict__ positions,
    _Float16* __restrict__ qc, _Float16* __restrict__ kc)
{
  const int idx = blockIdx.x * 256 + threadIdx.x;  // T*128 threads
  const int t = idx >> 7, d = idx & 127;
  const float invf = (float)pow(10000.0, -(double)d / 128.0);
  const float fr = (float)positions[t] * invf;
  const double fd = (double)fr;
  const float c = bf16_rt((float)cos(fd));
  const float s = bf16_rt((float)sin(fd));
  const _Float16* y = Y + (long long)t * 12288;
#pragma unroll
  for (int h = 0; h < 16; ++h) {
    const float qr = (float)y[h * 128 + d],        qi = (float)y[2048 + h * 128 + d];
    const float kr = (float)y[4096 + h * 128 + d], ki = (float)y[6144 + h * 128 + d];
    const long long ob = ((long long)h * 2048 + t) * 256 + d;
    qc[ob]       = (_Float16)(qr * c - qi * s);
    qc[ob + 128] = (_Float16)(qi * c + qr * s);
    kc[ob]       = (_Float16)(kr * c - ki * s);
    kc[ob + 128] = (_Float16)(ki * c + kr * s);
  }
}

// V transpose: Yqkv v-part -> vt [NH][256][T] fp16 (d-major for PV B-operand)
__global__ __launch_bounds__(256) void vtrans(
    const _Float16* __restrict__ Y, _Float16* __restrict__ vt)
{
  __shared__ float tile[64][65];
  const int t0 = blockIdx.x * 64, d0 = blockIdx.y * 64, h = blockIdx.z;
  const int tx = threadIdx.x & 63, ty = threadIdx.x >> 6;
  const int dd = d0 + tx;
  const int col = (dd < 128) ? (8192 + h * 128 + dd) : (10240 + h * 128 + (dd - 128));
  for (int rr = 0; rr < 16; ++rr) {
    const int tl = ty * 16 + rr;
    tile[tx][tl] = (float)Y[(long long)(t0 + tl) * 12288 + col];
  }
  __syncthreads();
  for (int rr = 0; rr < 16; ++rr) {
    const int dl = ty * 16 + rr;
    vt[((long long)h * 256 + (d0 + dl)) * 2048 + (t0 + tx)] = (_Float16)tile[dl][tx];
  }
}

// causal softmax: one WAVE per 8 rows, no barriers, all values in registers.
// Reads fp32 scores, writes P fp16 IN PLACE (row stride 2048 fp32 = 4096 fp16),
// zero-padded to the 128 boundary (exactly what the PV GEMM reads).
__global__ __launch_bounds__(256) void softmax_rows(float* __restrict__ Sbuf)
{
  const int wave = threadIdx.x >> 6, lane = threadIdx.x & 63;
  const int t0 = blockIdx.x * 32 + wave * 8;
  float* base = Sbuf + (long long)blockIdx.y * 2048 * 2048;
  for (int rr = 0; rr < 8; ++rr) {
    const int row = t0 + rr;
    float* rp = base + (long long)row * 2048;
    const int n = row + 1;
    const int npad = (n + 127) & ~127;
    v4f v[8];
    float m = -1e30f;
#pragma unroll
    for (int j = 0; j < 8; ++j) {
      const int c = j * 256 + lane * 4;
      if (c < npad) {
        v4f x = *(const v4f*)(rp + c);
        x[0] = (c + 0 < n) ? x[0] : -1e30f;
        x[1] = (c + 1 < n) ? x[1] : -1e30f;
        x[2] = (c + 2 < n) ? x[2] : -1e30f;
        x[3] = (c + 3 < n) ? x[3] : -1e30f;
        v[j] = x;
        m = fmaxf(m, fmaxf(fmaxf(x[0], x[1]), fmaxf(x[2], x[3])));
      } else {
        v[j] = (v4f){-1e30f, -1e30f, -1e30f, -1e30f};
      }
    }
    for (int o = 1; o < 64; o <<= 1) m = fmaxf(m, __shfl_xor(m, o, 64));
    float sum = 0.f;
#pragma unroll
    for (int j = 0; j < 8; ++j) {
      v4f e;
      e[0] = __expf(v[j][0] - m); e[1] = __expf(v[j][1] - m);
      e[2] = __expf(v[j][2] - m); e[3] = __expf(v[j][3] - m);
      v[j] = e;
      sum += e[0] + e[1] + e[2] + e[3];
    }
    for (int o = 1; o < 64; o <<= 1) sum += __shfl_xor(sum, o, 64);
    const float inv = 1.f / sum;
    _Float16* prow = (_Float16*)rp;
#pragma unroll
    for (int j = 0; j < 8; ++j) {
      const int c = j * 256 + lane * 4;
      if (c < npad) {
        v4h o;
        o[0] = (_Float16)(v[j][0] * inv); o[1] = (_Float16)(v[j][1] * inv);
        o[2] = (_Float16)(v[j][2] * inv); o[3] = (_Float16)(v[j][3] * inv);
        *(v4h*)(prow + c) = o;
      }
    }
  }
}

extern "C" void kernel_launch(void* const* d_in, const int* in_sizes, int n_in,
                              void* d_out, int out_size, void* d_ws, size_t ws_size,
                              hipStream_t stream) {
  const float* hr   = (const float*)d_in[0];
  const float* hi   = (const float*)d_in[1];
  const int*   pos  = (const int*)d_in[2];
  const float* Wq_r = (const float*)d_in[3];
  const float* Wq_i = (const float*)d_in[4];
  const float* Wk_r = (const float*)d_in[5];
  const float* Wk_i = (const float*)d_in[6];
  const float* Wv_r = (const float*)d_in[7];
  const float* Wv_i = (const float*)d_in[8];
  const float* Wo_r = (const float*)d_in[9];
  const float* Wo_i = (const float*)d_in[10];

  char* ws = (char*)d_ws;
  // layout (MB offsets); attn aliases dead Yqkv, Ac2 aliases dead Ac
  _Float16* Bqkv = (_Float16*)(ws);                    // 96MB
  _Float16* Bo   = (_Float16*)(ws + (96ll  << 20));    // 32MB
  _Float16* Ac   = (_Float16*)(ws + (128ll << 20));    // 16MB (reused as Ac2)
  _Float16* Yq   = (_Float16*)(ws + (144ll << 20));    // 48MB fp16
  float*    attn = (float*)   (ws + (144ll << 20));    // 32MB fp32 (alias)
  _Float16* qc   = (_Float16*)(ws + (192ll << 20));    // 16MB
  _Float16* kc   = (_Float16*)(ws + (208ll << 20));    // 16MB
  _Float16* vt   = (_Float16*)(ws + (224ll << 20));    // 16MB
  float*    Sbuf = (float*)   (ws + (240ll << 20));    // HG*16MB

  int HG = 16;   // heads per score-buffer pass, shrink to fit ws
  while (HG > 1 && (240ull << 20) + (size_t)HG * (16ull << 20) > ws_size) HG >>= 1;

  quant_rows<<<dim3(2048, 2), 256, 0, stream>>>(hr, hi, Ac, 2048, 4096);
  wprep<<<65536, 256, 0, stream>>>(Wq_r, Wq_i, Wk_r, Wk_i, Wv_r, Wv_i, Wo_r, Wo_i, Bqkv, Bo);
  // fused complex QKV projection: [qr|qi](2048x4096) @ Bqkv^T -> Yq (2048x12288)
  gemm_nt<EPI_F16, false, false><<<dim3(16, 96, 1), 256, 0, stream>>>(
      Ac, Bqkv, Yq, 2048, 12288, 4096, 4096, 4096, 12288, 0, 0, 0, 1.f, nullptr, 0);
  rope_kernel<<<1024, 256, 0, stream>>>(Yq, pos, qc, kc);
  vtrans<<<dim3(32, 4, 16), 256, 0, stream>>>(Yq, vt);

  for (int g = 0; g < 16 / HG; ++g) {
    const int h0 = g * HG;
    // scores: qc[h] (2048x256) @ kc[h]^T * 1/16 -> Sbuf fp32, skip masked blocks
    gemm_nt<EPI_SCORE, true, false><<<dim3(16, 16, HG), 256, 0, stream>>>(
        qc + (long long)h0 * 2048 * 256, kc + (long long)h0 * 2048 * 256, Sbuf,
        2048, 2048, 256, 256, 256, 2048,
        2048ll * 256, 2048ll * 256, 2048ll * 2048, 0.0625f, nullptr, 0);
    softmax_rows<<<dim3(64, HG), 256, 0, stream>>>(Sbuf);
    // PV: P (fp16 in Sbuf, lda=4096) @ vt[h]^T -> attn (r|i split), causal k-end
    gemm_nt<EPI_ATTN, false, true><<<dim3(16, 2, HG), 256, 0, stream>>>(
        (const _Float16*)Sbuf, vt + (long long)h0 * 256 * 2048, nullptr,
        2048, 256, 2048, 4096, 2048, 0,
        2048ll * 2048 * 2, 256ll * 2048, 0, 1.f, attn, h0);
  }

  quant_rows<<<dim3(2048, 2), 256, 0, stream>>>(attn, attn + 2048ll * 2048, Ac, 2048, 4096);
  // output projection -> d_out = [yr (T*H) | yi (T*H)] fp32
  gemm_nt<EPI_OUT, false, false><<<dim3(16, 32, 1), 256, 0, stream>>>(
      Ac, Bo, d_out, 2048, 4096, 4096, 4096, 4096, 0, 0, 0, 0, 1.f, nullptr, 0);
}

// Round 3
// 903.761 us; speedup vs baseline: 2.2463x; 2.2463x over previous
//
#include <hip/hip_runtime.h>

// ComplexNetAttention on gfx950.
// Pipeline: int8-fakequant -> fused complex QKV GEMM (fp16 MFMA, NT, K=4096;
//   q/k part -> Yq, v part stored TRANSPOSED to vt in-epilogue) -> cos/sin
//   table + vectorized RoPE -> fused flash attention (causal, online softmax)
//   -> fakequant -> out GEMM.
// GEMM template: 128x128 tile, BK=32, 256 thr (4 waves, 2x2 of 64x64), 4x4
// MFMA 16x16x32_f16 per wave, global_load_lds width-16 staging, XOR-swizzled
// LDS chunk layout (conflict-free, verified R2: SQ_LDS_BANK_CONFLICT=0).

typedef float v4f __attribute__((ext_vector_type(4)));
typedef _Float16 v8h __attribute__((ext_vector_type(8)));
typedef _Float16 v4h __attribute__((ext_vector_type(4)));

typedef const __attribute__((address_space(1))) void glob_void;
typedef __attribute__((address_space(3))) void lds_void;

__device__ __forceinline__ void gload16(const _Float16* gp, _Float16* lp) {
  __builtin_amdgcn_global_load_lds((glob_void*)gp, (lds_void*)lp, 16, 0, 0);
}

// bf16 round-trip (RNE) in fp32 — matches reference's bf16 cos/sin cache.
__device__ __forceinline__ float bf16_rt(float f) {
  union { float f; unsigned u; } a; a.f = f;
  unsigned r = (a.u + 0x7fffu + ((a.u >> 16) & 1u)) & 0xffff0000u;
  union { unsigned u; float f; } b; b.u = r;
  return b.f;
}

#define EPI_F16 0
#define EPI_VT  1
#define EPI_OUT 2

// NT GEMM: C[M][N] = A[M][K] @ B[N][K]^T, fp16 in, fp32 acc.
// EPI_F16: store fp16 row-major (ldc).  EPI_VT: v-projection, store transposed
// into vt[NH][256][2048] as packed v4h (4 consecutive t per acc reg group).
// EPI_OUT: fp32, split cols [yr|yi] into concatenated halves of d_out.
template<int EPI>
__global__ __launch_bounds__(256) void gemm_nt(
    const _Float16* __restrict__ A, const _Float16* __restrict__ B,
    void* __restrict__ Cv, int K, int lda, int ldb, int ldc,
    _Float16* __restrict__ vtout)
{
  const int m0 = blockIdx.x * 128, n0 = blockIdx.y * 128;

  __shared__ __align__(16) _Float16 As[128 * 32];
  __shared__ __align__(16) _Float16 Bs[128 * 32];

  const int tid = threadIdx.x, lane = tid & 63, wave = tid >> 6;
  // staging: tile 128 rows x 32 halfs = 8KB, 2 segs x 256 thr x 16B.
  // XOR chunk swizzle: global chunk (c ^ ((r>>1)&3)) lands at slot c of row r.
  const int off0 = tid * 8, off1 = 2048 + tid * 8;
  const int r0 = off0 >> 5, r1 = off1 >> 5;
  const int c0 = ((((off0 >> 3) & 3) ^ ((r0 >> 1) & 3)) << 3);
  const int c1 = ((((off1 >> 3) & 3) ^ ((r1 >> 1) & 3)) << 3);
  const _Float16* ga0 = A + (long long)(m0 + r0) * lda + c0;
  const _Float16* ga1 = A + (long long)(m0 + r1) * lda + c1;
  const _Float16* gb0 = B + (long long)(n0 + r0) * ldb + c0;
  const _Float16* gb1 = B + (long long)(n0 + r1) * ldb + c1;

  const int mr = (wave >> 1) * 64 + (lane & 15);
  const int nr = (wave & 1) * 64 + (lane & 15);
  const int kq = lane >> 4;

  v4f acc[4][4] = {};

  for (int k0 = 0; k0 < K; k0 += 32) {
    gload16(ga0 + k0, As + off0);
    gload16(ga1 + k0, As + off1);
    gload16(gb0 + k0, Bs + off0);
    gload16(gb1 + k0, Bs + off1);
    __syncthreads();
    v8h a[4], b[4];
#pragma unroll
    for (int i = 0; i < 4; ++i) {
      const int r = mr + i * 16;
      a[i] = *(const v8h*)&As[r * 32 + ((kq ^ ((r >> 1) & 3)) << 3)];
    }
#pragma unroll
    for (int j = 0; j < 4; ++j) {
      const int r = nr + j * 16;
      b[j] = *(const v8h*)&Bs[r * 32 + ((kq ^ ((r >> 1) & 3)) << 3)];
    }
#pragma unroll
    for (int i = 0; i < 4; ++i)
#pragma unroll
      for (int j = 0; j < 4; ++j)
        acc[i][j] = __builtin_amdgcn_mfma_f32_16x16x32_f16(a[i], b[j], acc[i][j], 0, 0, 0);
    __syncthreads();
  }

  // C/D layout (m89/m91-verified): col=lane&15, row=quad*4+reg
  const int cr = (wave >> 1) * 64 + (lane >> 4) * 4;
  const int cc = (wave & 1) * 64 + (lane & 15);
#pragma unroll
  for (int i = 0; i < 4; ++i)
#pragma unroll
    for (int j = 0; j < 4; ++j) {
      if (EPI == EPI_VT) {
        const int c = n0 + cc + j * 16;              // local v col 0..4095
        const int hh = (c & 2047) >> 7;
        const int dcol = (c < 2048) ? (c & 127) : (128 + (c & 127));
        const int row0 = m0 + cr + i * 16;           // multiple of 4
        v4h p;
#pragma unroll
        for (int r = 0; r < 4; ++r) p[r] = (_Float16)acc[i][j][r];
        *(v4h*)(vtout + ((long long)(hh * 256 + dcol)) * 2048 + row0) = p;
      } else {
#pragma unroll
        for (int r = 0; r < 4; ++r) {
          const int row = m0 + cr + i * 16 + r;
          const int col = n0 + cc + j * 16;
          const float v = acc[i][j][r];
          if (EPI == EPI_F16) {
            ((_Float16*)Cv)[(long long)row * ldc + col] = (_Float16)v;
          } else { // EPI_OUT
            float* O = (float*)Cv;
            if (col < 2048) O[(long long)row * 2048 + col] = v;
            else O[2048ll * 2048 + (long long)row * 2048 + (col - 2048)] = v;
          }
        }
      }
    }
}

// per-row int8 fake-quant of two [T][rowlen] fp32 sources -> fp16 [T][2*rowlen]
__global__ __launch_bounds__(256) void quant_rows(
    const float* __restrict__ s0, const float* __restrict__ s1,
    _Float16* __restrict__ dst, int rowlen, int dld)
{
  const int t = blockIdx.x, y = blockIdx.y;
  const float* src = (y ? s1 : s0) + (long long)t * rowlen;
  const int tid = threadIdx.x, lane = tid & 63, wave = tid >> 6;
  __shared__ float rbuf[4];
  float m = 0.f;
  for (int c = tid * 4; c < rowlen; c += 1024) {
    v4f v = *(const v4f*)(src + c);
    m = fmaxf(m, fmaxf(fmaxf(fabsf(v[0]), fabsf(v[1])), fmaxf(fabsf(v[2]), fabsf(v[3]))));
  }
  for (int o = 1; o < 64; o <<= 1) m = fmaxf(m, __shfl_xor(m, o, 64));
  if (lane == 0) rbuf[wave] = m;
  __syncthreads();
  m = fmaxf(fmaxf(rbuf[0], rbuf[1]), fmaxf(rbuf[2], rbuf[3]));
  const float scale = 127.f / fmaxf(m, 1e-5f);
  _Float16* d = dst + (long long)t * dld + (long long)y * rowlen;
  for (int c = tid * 4; c < rowlen; c += 1024) {
    v4f v = *(const v4f*)(src + c);
#pragma unroll
    for (int k = 0; k < 4; ++k) {
      float q = fminf(fmaxf(rintf(v[k] * scale), -128.f), 127.f);
      d[c + k] = (_Float16)(q / scale);
    }
  }
}

// Build concatenated complex weight matrices (fp16), 16 halfs/thread:
// Bqkv[12288][4096]: per (Wr,Wi): rows [Wr|Wi] then [Wi|-Wr]; Bo[4096][4096].
__global__ __launch_bounds__(256) void wprep(
    const float* __restrict__ Wq_r, const float* __restrict__ Wq_i,
    const float* __restrict__ Wk_r, const float* __restrict__ Wk_i,
    const float* __restrict__ Wv_r, const float* __restrict__ Wv_i,
    const float* __restrict__ Wo_r, const float* __restrict__ Wo_i,
    _Float16* __restrict__ Bqkv, _Float16* __restrict__ Bo)
{
  const int i = blockIdx.x * 256 + threadIdx.x;   // 16384 rows * 256 chunks
  const int n = i >> 8;
  const int cb = (i & 255) * 16;
  const float *sA, *sB; float sg; _Float16* dst; int j;
  if (n < 12288) {
    const int which = n >> 11; j = n & 2047;
    switch (which) {
      case 0: sA = Wq_r; sB = Wq_i; sg =  1.f; break;
      case 1: sA = Wq_i; sB = Wq_r; sg = -1.f; break;
      case 2: sA = Wk_r; sB = Wk_i; sg =  1.f; break;
      case 3: sA = Wk_i; sB = Wk_r; sg = -1.f; break;
      case 4: sA = Wv_r; sB = Wv_i; sg =  1.f; break;
      default: sA = Wv_i; sB = Wv_r; sg = -1.f; break;
    }
    dst = Bqkv + (long long)n * 4096;
  } else {
    const int n2 = n - 12288; const int which = n2 >> 11; j = n2 & 2047;
    if (which == 0) { sA = Wo_r; sB = Wo_i; sg = 1.f; }
    else            { sA = Wo_i; sB = Wo_r; sg = -1.f; }
    dst = Bo + (long long)n2 * 4096;
  }
  const float mult = (cb < 2048) ? 1.f : sg;
  const float* src = (cb < 2048) ? (sA + (long long)j * 2048 + cb)
                                 : (sB + (long long)j * 2048 + (cb - 2048));
  const v4f* s4 = (const v4f*)src;
  _Float16* d = dst + cb;
#pragma unroll
  for (int q = 0; q < 4; ++q) {
    const v4f v = s4[q];
    v4h o;
    o[0] = (_Float16)(v[0] * mult); o[1] = (_Float16)(v[1] * mult);
    o[2] = (_Float16)(v[2] * mult); o[3] = (_Float16)(v[3] * mult);
    *(v4h*)(d + q * 4) = o;
  }
}

// cos/sin table [T][128] float2, bf16-rounded — EXACT same math as before.
__global__ __launch_bounds__(256) void trig_kernel(
    const int* __restrict__ pos, float* __restrict__ cs)
{
  const int t = blockIdx.x * 2 + (threadIdx.x >> 7);
  const int d = threadIdx.x & 127;
  const float invf = (float)pow(10000.0, -(double)d / 128.0);
  const float fr = (float)pos[t] * invf;
  const double fd = (double)fr;
  cs[((long long)t * 128 + d) * 2]     = bf16_rt((float)cos(fd));
  cs[((long long)t * 128 + d) * 2 + 1] = bf16_rt((float)sin(fd));
}

// vectorized RoPE: Yq [T][8192] (qr|qi|kr|ki) -> qc/kc [NH][T][256] fp16
__global__ __launch_bounds__(256) void rope_kernel(
    const _Float16* __restrict__ Yq, const float* __restrict__ cs,
    _Float16* __restrict__ qc, _Float16* __restrict__ kc)
{
  const int idx = blockIdx.x * 256 + threadIdx.x;  // T*16*16 threads
  const int d0 = (idx & 15) * 8;
  const int h  = (idx >> 4) & 15;
  const int t  = idx >> 8;
  const _Float16* y = Yq + (long long)t * 8192 + h * 128 + d0;
  const v8h qr8 = *(const v8h*)(y);
  const v8h qi8 = *(const v8h*)(y + 2048);
  const v8h kr8 = *(const v8h*)(y + 4096);
  const v8h ki8 = *(const v8h*)(y + 6144);
  const float* cp = cs + ((long long)t * 128 + d0) * 2;
  v8h qro, qio, kro, kio;
#pragma unroll
  for (int u = 0; u < 8; ++u) {
    const float c = cp[u * 2], s = cp[u * 2 + 1];
    const float qr = (float)qr8[u], qi = (float)qi8[u];
    const float kr = (float)kr8[u], ki = (float)ki8[u];
    qro[u] = (_Float16)(qr * c - qi * s);
    qio[u] = (_Float16)(qi * c + qr * s);
    kro[u] = (_Float16)(kr * c - ki * s);
    kio[u] = (_Float16)(ki * c + kr * s);
  }
  _Float16* qo = qc + ((long long)h * 2048 + t) * 256 + d0;
  _Float16* ko = kc + ((long long)h * 2048 + t) * 256 + d0;
  *(v8h*)qo = qro; *(v8h*)(qo + 128) = qio;
  *(v8h*)ko = kro; *(v8h*)(ko + 128) = kio;
}

// Fused causal flash attention. One block = 64 Q-rows of one head.
// 4 waves as 2(m)x2(n). K-tile 64. D = 256 (r|i concat) for both QK^T and PV.
// Online softmax with cross-wave m/l merge through LDS. Scale 1/16 on S.
__global__ __launch_bounds__(256, 2) void flash_attn(
    const _Float16* __restrict__ qc, const _Float16* __restrict__ kc,
    const _Float16* __restrict__ vt, float* __restrict__ attn)
{
  __shared__ __align__(16) _Float16 Ks[64 * 256];
  __shared__ __align__(16) _Float16 Vs[256 * 64];
  __shared__ __align__(16) _Float16 Ps[64 * 72];   // pad 64->72 (A-frag reads)
  __shared__ float pmax[2][64];
  __shared__ float psum[2][64];

  const int h  = blockIdx.y;
  // load-balance remap: CU c tends to get blocks {c, c+256} -> qt + (31-qt)
  const int qt = ((h >> 3) & 1) ? (31 - (int)blockIdx.x) : (int)blockIdx.x;
  const int q0 = qt * 64;
  const int tid = threadIdx.x, lane = tid & 63, wave = tid >> 6;
  const int mi = wave >> 1, ni = wave & 1;
  const int quad = lane >> 4, l15 = lane & 15;

  const _Float16* qh = qc + (long long)h * 2048 * 256;
  const _Float16* kh = kc + (long long)h * 2048 * 256;
  const _Float16* vh = vt + (long long)h * 256 * 2048;

  // Q fragments in registers: wave's 32 rows, 8 k-chunks of 32
  v8h qf[2][8];
#pragma unroll
  for (int mt = 0; mt < 2; ++mt) {
    const int t = q0 + mi * 32 + mt * 16 + l15;
#pragma unroll
    for (int ks = 0; ks < 8; ++ks)
      qf[mt][ks] = *(const v8h*)(qh + (long long)t * 256 + ks * 32 + quad * 8);
  }

  float mrow[2][4], lrow[2][4];
  v4f acc_o[2][8];
#pragma unroll
  for (int mt = 0; mt < 2; ++mt)
#pragma unroll
    for (int r = 0; r < 4; ++r) { mrow[mt][r] = -1e30f; lrow[mt][r] = 0.f; }
#pragma unroll
  for (int mt = 0; mt < 2; ++mt)
#pragma unroll
    for (int nt = 0; nt < 8; ++nt) acc_o[mt][nt] = (v4f){0.f, 0.f, 0.f, 0.f};

  for (int st = 0; st <= qt; ++st) {
    const int s0 = st * 64;
    // stage K-tile [64][256] and V-tile [256][64] (XOR-swizzled 16B chunks)
#pragma unroll
    for (int it = 0; it < 8; ++it) {
      const int slot = it * 256 + tid;
      const int kr_ = slot >> 5, kch = slot & 31;
      const int gkc = (kch & 24) | ((kch & 7) ^ (kr_ & 7));
      gload16(kh + (long long)(s0 + kr_) * 256 + gkc * 8, Ks + slot * 8);
      const int vr_ = slot >> 3, vch = slot & 7;
      const int gvc = vch ^ (vr_ & 7);
      gload16(vh + (long long)vr_ * 2048 + s0 + gvc * 8, Vs + slot * 8);
    }
    __syncthreads();

    // S quarter = Q[mi-half] @ K[ni-half]^T
    v4f sa[2][2] = {};
#pragma unroll
    for (int ks = 0; ks < 8; ++ks) {
      v8h bk[2];
#pragma unroll
      for (int jn = 0; jn < 2; ++jn) {
        const int row = ni * 32 + jn * 16 + l15;
        const int ck = ks * 4 + quad;
        const int sc = (ck & 24) | ((ck & 7) ^ (row & 7));
        bk[jn] = *(const v8h*)(Ks + row * 256 + sc * 8);
      }
#pragma unroll
      for (int mt = 0; mt < 2; ++mt)
#pragma unroll
        for (int jn = 0; jn < 2; ++jn)
          sa[mt][jn] = __builtin_amdgcn_mfma_f32_16x16x32_f16(qf[mt][ks], bk[jn], sa[mt][jn], 0, 0, 0);
    }

    const bool diag = (st == qt);
    float pm[2][4];
#pragma unroll
    for (int mt = 0; mt < 2; ++mt)
#pragma unroll
      for (int r = 0; r < 4; ++r) pm[mt][r] = -1e30f;
#pragma unroll
    for (int mt = 0; mt < 2; ++mt)
#pragma unroll
      for (int jn = 0; jn < 2; ++jn)
#pragma unroll
        for (int r = 0; r < 4; ++r) {
          float v = sa[mt][jn][r] * 0.0625f;
          if (diag) {
            const int rl = mi * 32 + mt * 16 + quad * 4 + r;
            const int cl = ni * 32 + jn * 16 + l15;
            if (cl > rl) v = -1e30f;
          }
          sa[mt][jn][r] = v;
          pm[mt][r] = fmaxf(pm[mt][r], v);
        }
    // reduce over 16 cols (lanes within quad)
#pragma unroll
    for (int o = 1; o < 16; o <<= 1)
#pragma unroll
      for (int mt = 0; mt < 2; ++mt)
#pragma unroll
        for (int r = 0; r < 4; ++r)
          pm[mt][r] = fmaxf(pm[mt][r], __shfl_xor(pm[mt][r], o, 64));
    if (l15 == 0) {
#pragma unroll
      for (int mt = 0; mt < 2; ++mt)
#pragma unroll
        for (int r = 0; r < 4; ++r)
          pmax[ni][mi * 32 + mt * 16 + quad * 4 + r] = pm[mt][r];
    }
    __syncthreads();

    float al[2][4], ps[2][4];
#pragma unroll
    for (int mt = 0; mt < 2; ++mt)
#pragma unroll
      for (int r = 0; r < 4; ++r) {
        const int row = mi * 32 + mt * 16 + quad * 4 + r;
        const float mn = fmaxf(mrow[mt][r], fmaxf(pmax[0][row], pmax[1][row]));
        al[mt][r] = __expf(mrow[mt][r] - mn);
        mrow[mt][r] = mn;
        ps[mt][r] = 0.f;
      }
#pragma unroll
    for (int mt = 0; mt < 2; ++mt)
#pragma unroll
      for (int jn = 0; jn < 2; ++jn)
#pragma unroll
        for (int r = 0; r < 4; ++r) {
          const float e = __expf(sa[mt][jn][r] - mrow[mt][r]);
          ps[mt][r] += e;
          Ps[(mi * 32 + mt * 16 + quad * 4 + r) * 72 + ni * 32 + jn * 16 + l15] = (_Float16)e;
        }
#pragma unroll
    for (int o = 1; o < 16; o <<= 1)
#pragma unroll
      for (int mt = 0; mt < 2; ++mt)
#pragma unroll
        for (int r = 0; r < 4; ++r)
          ps[mt][r] += __shfl_xor(ps[mt][r], o, 64);
    if (l15 == 0) {
#pragma unroll
      for (int mt = 0; mt < 2; ++mt)
#pragma unroll
        for (int r = 0; r < 4; ++r)
          psum[ni][mi * 32 + mt * 16 + quad * 4 + r] = ps[mt][r];
    }
    __syncthreads();   // P + psum visible

#pragma unroll
    for (int mt = 0; mt < 2; ++mt)
#pragma unroll
      for (int r = 0; r < 4; ++r) {
        const int row = mi * 32 + mt * 16 + quad * 4 + r;
        lrow[mt][r] = lrow[mt][r] * al[mt][r] + psum[0][row] + psum[1][row];
      }
#pragma unroll
    for (int mt = 0; mt < 2; ++mt)
#pragma unroll
      for (int nt = 0; nt < 8; ++nt)
#pragma unroll
        for (int r = 0; r < 4; ++r)
          acc_o[mt][nt][r] *= al[mt][r];

    // O[mi-half rows][ni-half d] += P[mi-half][s] @ V[s][d]
#pragma unroll
    for (int kc2 = 0; kc2 < 2; ++kc2) {
      v8h pa[2];
#pragma unroll
      for (int mt = 0; mt < 2; ++mt) {
        const int row = mi * 32 + mt * 16 + l15;
        pa[mt] = *(const v8h*)(Ps + row * 72 + kc2 * 32 + quad * 8);
      }
#pragma unroll
      for (int nt = 0; nt < 8; ++nt) {
        const int vrow = ni * 128 + nt * 16 + l15;
        const int ck = kc2 * 4 + quad;
        const int sc = ck ^ (vrow & 7);
        const v8h vb = *(const v8h*)(Vs + vrow * 64 + sc * 8);
#pragma unroll
        for (int mt = 0; mt < 2; ++mt)
          acc_o[mt][nt] = __builtin_amdgcn_mfma_f32_16x16x32_f16(pa[mt], vb, acc_o[mt][nt], 0, 0, 0);
      }
    }
    __syncthreads();   // protect Ks/Vs before next stage
  }

  // epilogue: O/l -> attn (r-part at 0, i-part at +2048*2048 floats)
#pragma unroll
  for (int mt = 0; mt < 2; ++mt) {
    float inv[4];
#pragma unroll
    for (int r = 0; r < 4; ++r) inv[r] = 1.f / lrow[mt][r];
#pragma unroll
    for (int nt = 0; nt < 8; ++nt) {
      const int d = ni * 128 + nt * 16 + l15;
      float* dst = attn + ((d < 128) ? 0ll : (2048ll * 2048)) + (h * 128 + (d & 127));
#pragma unroll
      for (int r = 0; r < 4; ++r) {
        const int t = q0 + mi * 32 + mt * 16 + quad * 4 + r;
        dst[(long long)t * 2048] = acc_o[mt][nt][r] * inv[r];
      }
    }
  }
}

extern "C" void kernel_launch(void* const* d_in, const int* in_sizes, int n_in,
                              void* d_out, int out_size, void* d_ws, size_t ws_size,
                              hipStream_t stream) {
  const float* hr   = (const float*)d_in[0];
  const float* hi   = (const float*)d_in[1];
  const int*   pos  = (const int*)d_in[2];
  const float* Wq_r = (const float*)d_in[3];
  const float* Wq_i = (const float*)d_in[4];
  const float* Wk_r = (const float*)d_in[5];
  const float* Wk_i = (const float*)d_in[6];
  const float* Wv_r = (const float*)d_in[7];
  const float* Wv_i = (const float*)d_in[8];
  const float* Wo_r = (const float*)d_in[9];
  const float* Wo_i = (const float*)d_in[10];

  char* ws = (char*)d_ws;
  // layout (MB offsets), 224MB total; attn & cs alias dead Bqkv after gemms
  _Float16* Bqkv = (_Float16*)(ws);                    // 96MB
  float*    attn = (float*)   (ws);                    // 32MB (alias, post-QKV)
  float*    cs   = (float*)   (ws + (32ll  << 20));    // 2MB  (alias, post-QKV)
  _Float16* Bo   = (_Float16*)(ws + (96ll  << 20));    // 32MB
  _Float16* Ac   = (_Float16*)(ws + (128ll << 20));    // 16MB
  _Float16* Yq   = (_Float16*)(ws + (144ll << 20));    // 32MB (q,k only)
  _Float16* qc   = (_Float16*)(ws + (176ll << 20));    // 16MB
  _Float16* kc   = (_Float16*)(ws + (192ll << 20));    // 16MB
  _Float16* vt   = (_Float16*)(ws + (208ll << 20));    // 16MB

  quant_rows<<<dim3(2048, 2), 256, 0, stream>>>(hr, hi, Ac, 2048, 4096);
  wprep<<<16384, 256, 0, stream>>>(Wq_r, Wq_i, Wk_r, Wk_i, Wv_r, Wv_i, Wo_r, Wo_i, Bqkv, Bo);
  // q,k projection: [qr|qi](2048x4096) @ Bqkv[0:8192]^T -> Yq (2048x8192)
  gemm_nt<EPI_F16><<<dim3(16, 64), 256, 0, stream>>>(
      Ac, Bqkv, Yq, 4096, 4096, 4096, 8192, nullptr);
  // v projection: -> vt [NH][256][2048], transposed in-epilogue
  gemm_nt<EPI_VT><<<dim3(16, 32), 256, 0, stream>>>(
      Ac, Bqkv + 8192ll * 4096, nullptr, 4096, 4096, 4096, 0, vt);
  trig_kernel<<<1024, 256, 0, stream>>>(pos, cs);
  rope_kernel<<<2048, 256, 0, stream>>>(Yq, cs, qc, kc);
  flash_attn<<<dim3(32, 16), 256, 0, stream>>>(qc, kc, vt, attn);
  quant_rows<<<dim3(2048, 2), 256, 0, stream>>>(attn, attn + 2048ll * 2048, Ac, 2048, 4096);
  // output projection -> d_out = [yr (T*H) | yi (T*H)] fp32
  gemm_nt<EPI_OUT><<<dim3(16, 32), 256, 0, stream>>>(
      Ac, Bo, d_out, 4096, 4096, 4096, 0, nullptr);
}

// Round 5
// 796.103 us; speedup vs baseline: 2.5500x; 1.1352x over previous
//
#include <hip/hip_runtime.h>

// ComplexNetAttention on gfx950.
// Pipeline: int8-fakequant -> fused complex QKV GEMM (fp16 MFMA, NT, K=4096;
//   q/k cols -> Yq, v cols stored TRANSPOSED to vt in-epilogue) -> cos/sin
//   table + vectorized RoPE -> fused flash attention v2 (causal, online
//   softmax, K/V read DIRECT from L2, 2 barriers/stage) -> fakequant -> out GEMM.
// GEMM template: 128x128 tile, BK=32, 256 thr (4 waves, 2x2 of 64x64), 4x4
// MFMA 16x16x32_f16 per wave, global_load_lds width-16 staging, XOR-swizzled
// LDS chunk layout (conflict-free, verified R2: SQ_LDS_BANK_CONFLICT=0).

typedef float v4f __attribute__((ext_vector_type(4)));
typedef _Float16 v8h __attribute__((ext_vector_type(8)));
typedef _Float16 v4h __attribute__((ext_vector_type(4)));

typedef const __attribute__((address_space(1))) void glob_void;
typedef __attribute__((address_space(3))) void lds_void;

__device__ __forceinline__ void gload16(const _Float16* gp, _Float16* lp) {
  __builtin_amdgcn_global_load_lds((glob_void*)gp, (lds_void*)lp, 16, 0, 0);
}

// bf16 round-trip (RNE) in fp32 — matches reference's bf16 cos/sin cache.
__device__ __forceinline__ float bf16_rt(float f) {
  union { float f; unsigned u; } a; a.f = f;
  unsigned r = (a.u + 0x7fffu + ((a.u >> 16) & 1u)) & 0xffff0000u;
  union { unsigned u; float f; } b; b.u = r;
  return b.f;
}

#define EPI_QKV 0
#define EPI_OUT 1

// NT GEMM: C[M][N] = A[M][K] @ B[N][K]^T, fp16 in, fp32 acc.
// EPI_QKV: cols <8192 -> Yq fp16 row-major (ld 8192); cols >=8192 are the v
//   projection, stored transposed into vt[NH][256][2048] as packed v4h.
// EPI_OUT: fp32, split cols [yr|yi] into concatenated halves of d_out.
template<int EPI>
__global__ __launch_bounds__(256) void gemm_nt(
    const _Float16* __restrict__ A, const _Float16* __restrict__ B,
    void* __restrict__ Cv, int K, int lda, int ldb, int ldc,
    _Float16* __restrict__ vtout)
{
  const int m0 = blockIdx.x * 128, n0 = blockIdx.y * 128;

  __shared__ __align__(16) _Float16 As[128 * 32];
  __shared__ __align__(16) _Float16 Bs[128 * 32];

  const int tid = threadIdx.x, lane = tid & 63, wave = tid >> 6;
  // staging: tile 128 rows x 32 halfs = 8KB, 2 segs x 256 thr x 16B.
  // XOR chunk swizzle: global chunk (c ^ ((r>>1)&3)) lands at slot c of row r.
  const int off0 = tid * 8, off1 = 2048 + tid * 8;
  const int r0 = off0 >> 5, r1 = off1 >> 5;
  const int c0 = ((((off0 >> 3) & 3) ^ ((r0 >> 1) & 3)) << 3);
  const int c1 = ((((off1 >> 3) & 3) ^ ((r1 >> 1) & 3)) << 3);
  const _Float16* ga0 = A + (long long)(m0 + r0) * lda + c0;
  const _Float16* ga1 = A + (long long)(m0 + r1) * lda + c1;
  const _Float16* gb0 = B + (long long)(n0 + r0) * ldb + c0;
  const _Float16* gb1 = B + (long long)(n0 + r1) * ldb + c1;

  const int mr = (wave >> 1) * 64 + (lane & 15);
  const int nr = (wave & 1) * 64 + (lane & 15);
  const int kq = lane >> 4;

  v4f acc[4][4] = {};

  for (int k0 = 0; k0 < K; k0 += 32) {
    gload16(ga0 + k0, As + off0);
    gload16(ga1 + k0, As + off1);
    gload16(gb0 + k0, Bs + off0);
    gload16(gb1 + k0, Bs + off1);
    __syncthreads();
    v8h a[4], b[4];
#pragma unroll
    for (int i = 0; i < 4; ++i) {
      const int r = mr + i * 16;
      a[i] = *(const v8h*)&As[r * 32 + ((kq ^ ((r >> 1) & 3)) << 3)];
    }
#pragma unroll
    for (int j = 0; j < 4; ++j) {
      const int r = nr + j * 16;
      b[j] = *(const v8h*)&Bs[r * 32 + ((kq ^ ((r >> 1) & 3)) << 3)];
    }
#pragma unroll
    for (int i = 0; i < 4; ++i)
#pragma unroll
      for (int j = 0; j < 4; ++j)
        acc[i][j] = __builtin_amdgcn_mfma_f32_16x16x32_f16(a[i], b[j], acc[i][j], 0, 0, 0);
    __syncthreads();
  }

  // C/D layout (m89/m91-verified): col=lane&15, row=quad*4+reg
  const int cr = (wave >> 1) * 64 + (lane >> 4) * 4;
  const int cc = (wave & 1) * 64 + (lane & 15);
#pragma unroll
  for (int i = 0; i < 4; ++i)
#pragma unroll
    for (int j = 0; j < 4; ++j) {
      const int col = n0 + cc + j * 16;
      if (EPI == EPI_QKV && col >= 8192) {
        // v projection -> vt[NH][256][2048], packed 4 rows per store
        const int c = col - 8192;
        const int hh = (c & 2047) >> 7;
        const int dcol = (c < 2048) ? (c & 127) : (128 + (c & 127));
        const int row0 = m0 + cr + i * 16;           // multiple of 4
        v4h p;
#pragma unroll
        for (int r = 0; r < 4; ++r) p[r] = (_Float16)acc[i][j][r];
        *(v4h*)(vtout + ((long long)(hh * 256 + dcol)) * 2048 + row0) = p;
      } else {
#pragma unroll
        for (int r = 0; r < 4; ++r) {
          const int row = m0 + cr + i * 16 + r;
          const float v = acc[i][j][r];
          if (EPI == EPI_QKV) {
            ((_Float16*)Cv)[(long long)row * ldc + col] = (_Float16)v;
          } else { // EPI_OUT
            float* O = (float*)Cv;
            if (col < 2048) O[(long long)row * 2048 + col] = v;
            else O[2048ll * 2048 + (long long)row * 2048 + (col - 2048)] = v;
          }
        }
      }
    }
}

// per-row int8 fake-quant of two [2048][2048] fp32 sources -> fp16 [2048][4096]
// single global read: row cached in registers (8 floats/lane).
__global__ __launch_bounds__(256) void quant_rows(
    const float* __restrict__ s0, const float* __restrict__ s1,
    _Float16* __restrict__ dst)
{
  const int t = blockIdx.x, y = blockIdx.y;
  const float* src = (y ? s1 : s0) + (long long)t * 2048;
  const int tid = threadIdx.x, lane = tid & 63, wave = tid >> 6;
  __shared__ float rbuf[4];
  const v4f a = *(const v4f*)(src + tid * 4);
  const v4f b = *(const v4f*)(src + 1024 + tid * 4);
  float m = 0.f;
#pragma unroll
  for (int k = 0; k < 4; ++k)
    m = fmaxf(m, fmaxf(fabsf(a[k]), fabsf(b[k])));
  for (int o = 1; o < 64; o <<= 1) m = fmaxf(m, __shfl_xor(m, o, 64));
  if (lane == 0) rbuf[wave] = m;
  __syncthreads();
  m = fmaxf(fmaxf(rbuf[0], rbuf[1]), fmaxf(rbuf[2], rbuf[3]));
  const float scale = 127.f / fmaxf(m, 1e-5f);
  const float inv = 1.f / scale;
  _Float16* d = dst + (long long)t * 4096 + (long long)y * 2048 + tid * 4;
  v4h qa, qb;
#pragma unroll
  for (int k = 0; k < 4; ++k) {
    qa[k] = (_Float16)(fminf(fmaxf(rintf(a[k] * scale), -128.f), 127.f) * inv);
    qb[k] = (_Float16)(fminf(fmaxf(rintf(b[k] * scale), -128.f), 127.f) * inv);
  }
  *(v4h*)d = qa;
  *(v4h*)(d + 1024) = qb;
}

// Build concatenated complex weight matrices (fp16): read each W element ONCE,
// write to its two destinations. B layout per pair p (q,k,v at p*4096*4096):
// rows [Wr|Wi] ; rows+2048 [Wi|-Wr].
__global__ __launch_bounds__(256) void wprep(
    const float* __restrict__ Wq_r, const float* __restrict__ Wq_i,
    const float* __restrict__ Wk_r, const float* __restrict__ Wk_i,
    const float* __restrict__ Wv_r, const float* __restrict__ Wv_i,
    const float* __restrict__ Wo_r, const float* __restrict__ Wo_i,
    _Float16* __restrict__ Bqkv, _Float16* __restrict__ Bo)
{
  const float* Ws[8] = {Wq_r, Wq_i, Wk_r, Wk_i, Wv_r, Wv_i, Wo_r, Wo_i};
  const int i = blockIdx.x * 256 + threadIdx.x;  // 8 W * 2048 rows * 128 chunks
  const int w = i >> 18;
  const int rem = i & 262143;
  const int j = rem >> 7;
  const int cb = (rem & 127) * 16;
  const float* src = Ws[w] + (long long)j * 2048 + cb;
  // R4 BUG FIX: pair block is 4096 rows x 4096 cols = 4096*4096 elements
  // (was 2048*4096 -> K/V pairs overwrote halves of Q/K blocks).
  _Float16* Bp = (w < 6) ? (Bqkv + (long long)(w >> 1) * 4096 * 4096) : Bo;
  const int isI = w & 1;
  _Float16* d1 = Bp + (long long)j * 4096 + (isI ? 2048 + cb : cb);
  _Float16* d2 = Bp + (long long)(2048 + j) * 4096 + (isI ? cb : 2048 + cb);
  const float sg2 = isI ? 1.f : -1.f;
#pragma unroll
  for (int q = 0; q < 4; ++q) {
    const v4f v = *(const v4f*)(src + q * 4);
    v4h o1, o2;
#pragma unroll
    for (int k = 0; k < 4; ++k) {
      o1[k] = (_Float16)v[k];
      o2[k] = (_Float16)(v[k] * sg2);
    }
    *(v4h*)(d1 + q * 4) = o1;
    *(v4h*)(d2 + q * 4) = o2;
  }
}

// cos/sin table [T][128] float2, bf16-rounded — exact same math as reference.
__global__ __launch_bounds__(256) void trig_kernel(
    const int* __restrict__ pos, float* __restrict__ cs)
{
  const int t = blockIdx.x * 2 + (threadIdx.x >> 7);
  const int d = threadIdx.x & 127;
  const float invf = (float)pow(10000.0, -(double)d / 128.0);
  const float fr = (float)pos[t] * invf;
  const double fd = (double)fr;
  cs[((long long)t * 128 + d) * 2]     = bf16_rt((float)cos(fd));
  cs[((long long)t * 128 + d) * 2 + 1] = bf16_rt((float)sin(fd));
}

// vectorized RoPE: Yq [T][8192] (qr|qi|kr|ki) -> qc/kc [NH][T][256] fp16
__global__ __launch_bounds__(256) void rope_kernel(
    const _Float16* __restrict__ Yq, const float* __restrict__ cs,
    _Float16* __restrict__ qc, _Float16* __restrict__ kc)
{
  const int idx = blockIdx.x * 256 + threadIdx.x;  // T*16*16 threads
  const int d0 = (idx & 15) * 8;
  const int h  = (idx >> 4) & 15;
  const int t  = idx >> 8;
  const _Float16* y = Yq + (long long)t * 8192 + h * 128 + d0;
  const v8h qr8 = *(const v8h*)(y);
  const v8h qi8 = *(const v8h*)(y + 2048);
  const v8h kr8 = *(const v8h*)(y + 4096);
  const v8h ki8 = *(const v8h*)(y + 6144);
  const float* cp = cs + ((long long)t * 128 + d0) * 2;
  v8h qro, qio, kro, kio;
#pragma unroll
  for (int u = 0; u < 8; ++u) {
    const float c = cp[u * 2], s = cp[u * 2 + 1];
    const float qr = (float)qr8[u], qi = (float)qi8[u];
    const float kr = (float)kr8[u], ki = (float)ki8[u];
    qro[u] = (_Float16)(qr * c - qi * s);
    qio[u] = (_Float16)(qi * c + qr * s);
    kro[u] = (_Float16)(kr * c - ki * s);
    kio[u] = (_Float16)(ki * c + kr * s);
  }
  _Float16* qo = qc + ((long long)h * 2048 + t) * 256 + d0;
  _Float16* ko = kc + ((long long)h * 2048 + t) * 256 + d0;
  *(v8h*)qo = qro; *(v8h*)(qo + 128) = qio;
  *(v8h*)ko = kro; *(v8h*)(ko + 128) = kio;
}

// Fused causal flash attention v2. One block = 64 Q-rows of one head,
// 4 waves as 2(m)x2(n), K-tile 64, D=256 (r|i concat).
// K and V fragments read DIRECT from global (L2-resident, 1MB/head) — no
// LDS staging, no staging/tail barriers: 2 barriers per stage (softmax merge).
// Softmax in exp2 domain; scale (log2e/16) pre-folded into Q fragments.
__global__ __launch_bounds__(256, 2) void flash_attn(
    const _Float16* __restrict__ qc, const _Float16* __restrict__ kc,
    const _Float16* __restrict__ vt, float* __restrict__ attn)
{
  __shared__ __align__(16) _Float16 Ps[64 * 72];   // pad 64->72 (A-frag reads)
  __shared__ float pmax[2][64];
  __shared__ float psum[2][64];

  const int h  = blockIdx.y;
  // load-balance remap: pair small-qt with large-qt across heads
  const int qt = ((h >> 3) & 1) ? (31 - (int)blockIdx.x) : (int)blockIdx.x;
  const int q0 = qt * 64;
  const int tid = threadIdx.x, lane = tid & 63, wave = tid >> 6;
  const int mi = wave >> 1, ni = wave & 1;
  const int quad = lane >> 4, l15 = lane & 15;

  const _Float16* qh = qc + (long long)h * 2048 * 256;
  const _Float16* kh = kc + (long long)h * 2048 * 256;
  const _Float16* vh = vt + (long long)h * 256 * 2048;

  // Q fragments in registers, pre-scaled by log2(e)/16 (exp2-domain softmax)
  const _Float16 scl = (_Float16)0.09016844f;
  v8h qf[2][8];
#pragma unroll
  for (int mt = 0; mt < 2; ++mt) {
    const int t = q0 + mi * 32 + mt * 16 + l15;
#pragma unroll
    for (int ks = 0; ks < 8; ++ks) {
      v8h q = *(const v8h*)(qh + (long long)t * 256 + ks * 32 + quad * 8);
#pragma unroll
      for (int u = 0; u < 8; ++u) q[u] *= scl;
      qf[mt][ks] = q;
    }
  }

  float mrow[2][4], lrow[2][4];
  v4f acc_o[2][8];
#pragma unroll
  for (int mt = 0; mt < 2; ++mt)
#pragma unroll
    for (int r = 0; r < 4; ++r) { mrow[mt][r] = -1e30f; lrow[mt][r] = 0.f; }
#pragma unroll
  for (int mt = 0; mt < 2; ++mt)
#pragma unroll
    for (int nt = 0; nt < 8; ++nt) acc_o[mt][nt] = (v4f){0.f, 0.f, 0.f, 0.f};

  for (int st = 0; st <= qt; ++st) {
    const int s0 = st * 64;

    // S quarter = Q[mi-half] @ K[ni-half]^T, K direct from global (L2-hot)
    v4f sa[2][2] = {};
#pragma unroll
    for (int ks = 0; ks < 8; ++ks) {
      v8h bk[2];
#pragma unroll
      for (int jn = 0; jn < 2; ++jn)
        bk[jn] = *(const v8h*)(kh + (long long)(s0 + ni * 32 + jn * 16 + l15) * 256
                               + ks * 32 + quad * 8);
#pragma unroll
      for (int mt = 0; mt < 2; ++mt)
#pragma unroll
        for (int jn = 0; jn < 2; ++jn)
          sa[mt][jn] = __builtin_amdgcn_mfma_f32_16x16x32_f16(qf[mt][ks], bk[jn], sa[mt][jn], 0, 0, 0);
    }

    const bool diag = (st == qt);
    float pm[2][4];
#pragma unroll
    for (int mt = 0; mt < 2; ++mt)
#pragma unroll
      for (int r = 0; r < 4; ++r) pm[mt][r] = -1e30f;
#pragma unroll
    for (int mt = 0; mt < 2; ++mt)
#pragma unroll
      for (int jn = 0; jn < 2; ++jn)
#pragma unroll
        for (int r = 0; r < 4; ++r) {
          float v = sa[mt][jn][r];          // already log2-scaled
          if (diag) {
            const int rl = mi * 32 + mt * 16 + quad * 4 + r;
            const int cl = ni * 32 + jn * 16 + l15;
            if (cl > rl) v = -1e30f;
          }
          sa[mt][jn][r] = v;
          pm[mt][r] = fmaxf(pm[mt][r], v);
        }
#pragma unroll
    for (int o = 1; o < 16; o <<= 1)
#pragma unroll
      for (int mt = 0; mt < 2; ++mt)
#pragma unroll
        for (int r = 0; r < 4; ++r)
          pm[mt][r] = fmaxf(pm[mt][r], __shfl_xor(pm[mt][r], o, 64));
    if (l15 == 0) {
#pragma unroll
      for (int mt = 0; mt < 2; ++mt)
#pragma unroll
        for (int r = 0; r < 4; ++r)
          pmax[ni][mi * 32 + mt * 16 + quad * 4 + r] = pm[mt][r];
    }
    __syncthreads();   // B1: pmax visible

    float al[2][4], ps[2][4];
#pragma unroll
    for (int mt = 0; mt < 2; ++mt)
#pragma unroll
      for (int r = 0; r < 4; ++r) {
        const int row = mi * 32 + mt * 16 + quad * 4 + r;
        const float mn = fmaxf(mrow[mt][r], fmaxf(pmax[0][row], pmax[1][row]));
        al[mt][r] = __builtin_amdgcn_exp2f(mrow[mt][r] - mn);
        mrow[mt][r] = mn;
        ps[mt][r] = 0.f;
      }
#pragma unroll
    for (int mt = 0; mt < 2; ++mt)
#pragma unroll
      for (int jn = 0; jn < 2; ++jn)
#pragma unroll
        for (int r = 0; r < 4; ++r) {
          const float e = __builtin_amdgcn_exp2f(sa[mt][jn][r] - mrow[mt][r]);
          ps[mt][r] += e;
          Ps[(mi * 32 + mt * 16 + quad * 4 + r) * 72 + ni * 32 + jn * 16 + l15] = (_Float16)e;
        }
#pragma unroll
    for (int o = 1; o < 16; o <<= 1)
#pragma unroll
      for (int mt = 0; mt < 2; ++mt)
#pragma unroll
        for (int r = 0; r < 4; ++r)
          ps[mt][r] += __shfl_xor(ps[mt][r], o, 64);
    if (l15 == 0) {
#pragma unroll
      for (int mt = 0; mt < 2; ++mt)
#pragma unroll
        for (int r = 0; r < 4; ++r)
          psum[ni][mi * 32 + mt * 16 + quad * 4 + r] = ps[mt][r];
    }
    __syncthreads();   // B2: Ps + psum visible

#pragma unroll
    for (int mt = 0; mt < 2; ++mt)
#pragma unroll
      for (int r = 0; r < 4; ++r) {
        const int row = mi * 32 + mt * 16 + quad * 4 + r;
        lrow[mt][r] = lrow[mt][r] * al[mt][r] + psum[0][row] + psum[1][row];
      }
#pragma unroll
    for (int mt = 0; mt < 2; ++mt)
#pragma unroll
      for (int nt = 0; nt < 8; ++nt)
#pragma unroll
        for (int r = 0; r < 4; ++r)
          acc_o[mt][nt][r] *= al[mt][r];

    // O += P @ V ; P from LDS, V direct from global (L2-hot)
#pragma unroll
    for (int kc2 = 0; kc2 < 2; ++kc2) {
      v8h pa[2];
#pragma unroll
      for (int mt = 0; mt < 2; ++mt) {
        const int row = mi * 32 + mt * 16 + l15;
        pa[mt] = *(const v8h*)(Ps + row * 72 + kc2 * 32 + quad * 8);
      }
#pragma unroll
      for (int nt = 0; nt < 8; ++nt) {
        const v8h vb = *(const v8h*)(vh + (long long)(ni * 128 + nt * 16 + l15) * 2048
                                     + s0 + kc2 * 32 + quad * 8);
#pragma unroll
        for (int mt = 0; mt < 2; ++mt)
          acc_o[mt][nt] = __builtin_amdgcn_mfma_f32_16x16x32_f16(pa[mt], vb, acc_o[mt][nt], 0, 0, 0);
      }
    }
    // no tail barrier: next-stage Ps/pmax writes are gated by B1/B2 above
  }

  // epilogue: O/l -> attn (r-part at 0, i-part at +2048*2048 floats)
#pragma unroll
  for (int mt = 0; mt < 2; ++mt) {
    float inv[4];
#pragma unroll
    for (int r = 0; r < 4; ++r) inv[r] = 1.f / lrow[mt][r];
#pragma unroll
    for (int nt = 0; nt < 8; ++nt) {
      const int d = ni * 128 + nt * 16 + l15;
      float* dst = attn + ((d < 128) ? 0ll : (2048ll * 2048)) + (h * 128 + (d & 127));
#pragma unroll
      for (int r = 0; r < 4; ++r) {
        const int t = q0 + mi * 32 + mt * 16 + quad * 4 + r;
        dst[(long long)t * 2048] = acc_o[mt][nt][r] * inv[r];
      }
    }
  }
}

extern "C" void kernel_launch(void* const* d_in, const int* in_sizes, int n_in,
                              void* d_out, int out_size, void* d_ws, size_t ws_size,
                              hipStream_t stream) {
  const float* hr   = (const float*)d_in[0];
  const float* hi   = (const float*)d_in[1];
  const int*   pos  = (const int*)d_in[2];
  const float* Wq_r = (const float*)d_in[3];
  const float* Wq_i = (const float*)d_in[4];
  const float* Wk_r = (const float*)d_in[5];
  const float* Wk_i = (const float*)d_in[6];
  const float* Wv_r = (const float*)d_in[7];
  const float* Wv_i = (const float*)d_in[8];
  const float* Wo_r = (const float*)d_in[9];
  const float* Wo_i = (const float*)d_in[10];

  char* ws = (char*)d_ws;
  // layout (MB offsets), 224MB total; attn & cs alias dead Bqkv after QKV GEMM
  _Float16* Bqkv = (_Float16*)(ws);                    // 96MB
  float*    attn = (float*)   (ws);                    // 32MB (alias, post-QKV)
  float*    cs   = (float*)   (ws + (32ll  << 20));    // 2MB  (alias, post-QKV)
  _Float16* Bo   = (_Float16*)(ws + (96ll  << 20));    // 32MB
  _Float16* Ac   = (_Float16*)(ws + (128ll << 20));    // 16MB
  _Float16* Yq   = (_Float16*)(ws + (144ll << 20));    // 32MB (q,k only)
  _Float16* qc   = (_Float16*)(ws + (176ll << 20));    // 16MB
  _Float16* kc   = (_Float16*)(ws + (192ll << 20));    // 16MB
  _Float16* vt   = (_Float16*)(ws + (208ll << 20));    // 16MB

  quant_rows<<<dim3(2048, 2), 256, 0, stream>>>(hr, hi, Ac);
  wprep<<<8192, 256, 0, stream>>>(Wq_r, Wq_i, Wk_r, Wk_i, Wv_r, Wv_i, Wo_r, Wo_i, Bqkv, Bo);
  // fused QKV: [qr|qi](2048x4096) @ Bqkv(12288x4096)^T -> Yq (q,k) + vt (v)
  gemm_nt<EPI_QKV><<<dim3(16, 96), 256, 0, stream>>>(
      Ac, Bqkv, Yq, 4096, 4096, 4096, 8192, vt);
  trig_kernel<<<1024, 256, 0, stream>>>(pos, cs);
  rope_kernel<<<2048, 256, 0, stream>>>(Yq, cs, qc, kc);
  flash_attn<<<dim3(32, 16), 256, 0, stream>>>(qc, kc, vt, attn);
  quant_rows<<<dim3(2048, 2), 256, 0, stream>>>(attn, attn + 2048ll * 2048, Ac);
  // output projection -> d_out = [yr (T*H) | yi (T*H)] fp32
  gemm_nt<EPI_OUT><<<dim3(16, 32), 256, 0, stream>>>(
      Ac, Bo, d_out, 4096, 4096, 4096, 0, nullptr);
}